// Round 1
// baseline (1156.911 us; speedup 1.0000x reference)
//
#include <hip/hip_runtime.h>

// ---------------------------------------------------------------------------
// MoE FFN (SwiGLU, top-2 of 8 experts + shared expert), MI355X gfx950.
// Sparse grouped-GEMM formulation: 309 GFLOP instead of reference's 927.
// bf16 MFMA (16x16x32), fp32 accumulate; routing computed in fp32 (exact).
// ws layout (~231 MB): meta/slots | h_bf16 | w1c | w3c | w2c | G
// ---------------------------------------------------------------------------

#define T_TOK 8192
#define DDIM  1024
#define HDIM  2048
#define NEXP  8
#define NSLOT 24576        // 2*T routed + T shared
#define MAX_TILES 200      // 64 shared + <=136 routed m-tiles of 128

typedef __attribute__((ext_vector_type(8))) __bf16 bf16x8;
typedef __attribute__((ext_vector_type(4))) __bf16 bf16x4;
typedef __attribute__((ext_vector_type(4))) float  f32x4;

__device__ __forceinline__ void gload16(const void* g, void* l) {
  // async global->LDS, 16B per lane; LDS dest = wave-uniform base + lane*16
  __builtin_amdgcn_global_load_lds(
      (const __attribute__((address_space(1))) void*)g,
      (__attribute__((address_space(3))) void*)l, 16, 0, 0);
}

// ---------------- fp32 -> bf16 convert (vector x4) -------------------------
__global__ __launch_bounds__(256) void cvt_f32_bf16(
    const float* __restrict__ s, __bf16* __restrict__ d, int n4) {
  int i = blockIdx.x * 256 + threadIdx.x;
  if (i >= n4) return;
  f32x4 v = ((const f32x4*)s)[i];
  bf16x4 o;
  o[0] = (__bf16)v[0]; o[1] = (__bf16)v[1];
  o[2] = (__bf16)v[2]; o[3] = (__bf16)v[3];
  ((bf16x4*)d)[i] = o;
}

// ---------------- gate: softmax -> top2 -> renorm (fp32 exact) -------------
__global__ __launch_bounds__(256) void gate_kernel(
    const float* __restrict__ h, const float* __restrict__ Wg,
    int* __restrict__ top_e, float* __restrict__ top_w, int* __restrict__ counts) {
  int wv = threadIdx.x >> 6, lane = threadIdx.x & 63;
  int t = blockIdx.x * 4 + wv;
  const float* x = h + (size_t)t * DDIM;
  float acc[NEXP];
#pragma unroll
  for (int e = 0; e < NEXP; e++) acc[e] = 0.f;
  for (int i = lane; i < DDIM; i += 64) {
    float xv = x[i];
#pragma unroll
    for (int e = 0; e < NEXP; e++) acc[e] = fmaf(xv, Wg[e * DDIM + i], acc[e]);
  }
#pragma unroll
  for (int e = 0; e < NEXP; e++) {
#pragma unroll
    for (int off = 32; off > 0; off >>= 1) acc[e] += __shfl_xor(acc[e], off);
  }
  if (lane == 0) {
    int i1 = 0; float v1 = acc[0];
#pragma unroll
    for (int e = 1; e < NEXP; e++) if (acc[e] > v1) { v1 = acc[e]; i1 = e; }
    int i2 = -1; float v2 = -1e30f;
#pragma unroll
    for (int e = 0; e < NEXP; e++) if (e != i1 && acc[e] > v2) { v2 = acc[e]; i2 = e; }
    // top-2 renormalized softmax weights (denominator cancels)
    float e2 = __expf(v2 - v1);
    float w1 = 1.f / (1.f + e2);
    top_e[2 * t] = i1; top_e[2 * t + 1] = i2;
    top_w[2 * t] = w1; top_w[2 * t + 1] = e2 * w1;
    atomicAdd(&counts[i1], 1);
    atomicAdd(&counts[i2], 1);
  }
}

// ---------------- offsets + tile table (single thread, trivial) ------------
// meta: counts@0, cursor@16, offsets@32, ntiles@48 (ints)
__global__ void build_meta(int* __restrict__ meta, int4* __restrict__ table) {
  if (threadIdx.x != 0) return;
  int* counts = meta; int* cursor = meta + 16; int* offsets = meta + 32;
  int off = 0;
  for (int e = 0; e < NEXP; e++) { offsets[e] = off; off += counts[e]; cursor[e] = 0; }
  offsets[NEXP] = off;              // routed total = 16384; shared slots follow
  offsets[NEXP + 1] = off + T_TOK;
  int nt = 0;
  // shared-expert tiles FIRST (table[0..64)): enables non-atomic y store launch
  for (int lt = 0; lt < T_TOK / 128; lt++)
    table[nt++] = make_int4(NEXP, off + lt * 128, 128, 0);
  for (int e = 0; e < NEXP; e++) {
    int c = counts[e], s = offsets[e];
    for (int lt = 0; lt * 128 < c; lt++)
      table[nt++] = make_int4(e, s + lt * 128, min(128, c - lt * 128), 0);
  }
  meta[48] = nt;
  for (; nt < MAX_TILES; nt++) table[nt] = make_int4(-1, 0, 0, 0);
}

// ---------------- scatter tokens into per-expert slot lists ----------------
__global__ __launch_bounds__(256) void scatter_kernel(
    const int* __restrict__ top_e, const float* __restrict__ top_w,
    int* __restrict__ meta, int* __restrict__ slot_token, float* __restrict__ slot_w) {
  int t = blockIdx.x * 256 + threadIdx.x;
  int* cursor = meta + 16; const int* offsets = meta + 32;
#pragma unroll
  for (int k = 0; k < 2; k++) {
    int e = top_e[2 * t + k];
    int pos = offsets[e] + atomicAdd(&cursor[e], 1);
    slot_token[pos] = t; slot_w[pos] = top_w[2 * t + k];
  }
  int pos = offsets[NEXP] + t;   // shared expert slot (weight 1)
  slot_token[pos] = t; slot_w[pos] = 1.0f;
}

// ---------------- grouped GEMM -------------------------------------------
// C[M,N] = A[M,K] * B[N,K]^T per tile-table entry {expert, slot0, rows}.
// DUAL:  A = h_bf16 gathered by slot_token; B1=W1[e], B3=W3[e];
//        out G[slot, n] = silu(c1) * c3 (bf16)
// !DUAL: A = G rows (contiguous slots); B1=W2[e];
//        out y[token, n] (+)= slot_w * acc  (ATOMIC => atomicAdd)
// 128x128x64 tiles, 4 waves (2x2 of 64x64), 16x16x32 bf16 MFMA.
// LDS: XOR chunk swizzle (phys_chunk = kc ^ (row&7)) -> 2-way-max bank
// aliasing on ds_read_b128 while keeping global_load_lds dests contiguous
// (gather picks the swizzled global source per lane).
template <bool DUAL, bool ATOMIC>
__global__ __launch_bounds__(256) void moe_gemm(
    const __bf16* __restrict__ Abase, const __bf16* __restrict__ B1base,
    const __bf16* __restrict__ B3base, const int4* __restrict__ table,
    const int* __restrict__ slot_token, const float* __restrict__ slot_w,
    __bf16* __restrict__ Gout, float* __restrict__ Yout, int K, int N) {
  int4 te = table[blockIdx.x];
  if (te.x < 0) return;
  const int expert = te.x, slot0 = te.y, rows = te.z;
  const int n0 = blockIdx.y * 128;
  const int tid = threadIdx.x;
  const int lane = tid & 63, wave = tid >> 6;
  const int wm = (wave & 1) * 64, wn = (wave >> 1) * 64;

  __shared__ __align__(16) unsigned char lds[DUAL ? 49152 : 32768];

  // --- staging pointers: thread handles rows r = 32*i + tid/8, phys chunk tid&7
  const int sub = tid >> 3, pc = tid & 7;
  const __bf16* B1 = B1base + (size_t)expert * N * K;
  const __bf16* B3 = DUAL ? (B3base + (size_t)expert * N * K) : (const __bf16*)nullptr;
  const __bf16* aptr[4]; const __bf16* b1p[4]; const __bf16* b3p[4];
#pragma unroll
  for (int i = 0; i < 4; i++) {
    int r = 32 * i + sub;
    int rr = min(r, rows - 1);  // clamp pad rows to a valid source
    size_t arow = DUAL ? (size_t)slot_token[slot0 + rr] : (size_t)(slot0 + rr);
    int koff = ((pc ^ (r & 7)) << 3);   // swizzled logical k offset (elems)
    aptr[i] = Abase + arow * (size_t)K + koff;
    b1p[i] = B1 + (size_t)(n0 + r) * K + koff;
    if (DUAL) b3p[i] = B3 + (size_t)(n0 + r) * K + koff;
  }

  f32x4 acc1[4][4] = {};
  f32x4 acc3[4][4] = {};
  const int q = lane >> 4, ln = lane & 15;

  for (int k0 = 0; k0 < K; k0 += 64) {
#pragma unroll
    for (int i = 0; i < 4; i++)
      gload16(aptr[i] + k0, lds + i * 4096 + wave * 1024);
#pragma unroll
    for (int i = 0; i < 4; i++)
      gload16(b1p[i] + k0, lds + 16384 + i * 4096 + wave * 1024);
    if (DUAL) {
#pragma unroll
      for (int i = 0; i < 4; i++)
        gload16(b3p[i] + k0, lds + 32768 + i * 4096 + wave * 1024);
    }
    __syncthreads();   // drains vmcnt (global_load_lds) per compiler semantics
#pragma unroll
    for (int ks = 0; ks < 2; ks++) {
      bf16x8 af[4], b1f[4], b3f[4];
#pragma unroll
      for (int i = 0; i < 4; i++) {
        int row = wm + 16 * i + ln;
        af[i] = *(const bf16x8*)(lds + ((row * 8 + ((ks * 4 + q) ^ (row & 7))) << 4));
        int col = wn + 16 * i + ln;
        b1f[i] = *(const bf16x8*)(lds + 16384 + ((col * 8 + ((ks * 4 + q) ^ (col & 7))) << 4));
        if (DUAL)
          b3f[i] = *(const bf16x8*)(lds + 32768 + ((col * 8 + ((ks * 4 + q) ^ (col & 7))) << 4));
      }
#pragma unroll
      for (int i = 0; i < 4; i++) {
#pragma unroll
        for (int j = 0; j < 4; j++) {
          acc1[i][j] = __builtin_amdgcn_mfma_f32_16x16x32_bf16(af[i], b1f[j], acc1[i][j], 0, 0, 0);
          if (DUAL)
            acc3[i][j] = __builtin_amdgcn_mfma_f32_16x16x32_bf16(af[i], b3f[j], acc3[i][j], 0, 0, 0);
        }
      }
    }
    __syncthreads();
  }

  // --- epilogue; C/D layout: col = lane&15, row = (lane>>4)*4 + reg
#pragma unroll
  for (int i = 0; i < 4; i++) {
#pragma unroll
    for (int r = 0; r < 4; r++) {
      int m = wm + 16 * i + q * 4 + r;
      if (m < rows) {
        int slot = slot0 + m;
        if (DUAL) {
          __bf16* grow = Gout + (size_t)slot * N + n0 + wn + ln;
#pragma unroll
          for (int j = 0; j < 4; j++) {
            float c1 = acc1[i][j][r], c3 = acc3[i][j][r];
            float g = (c1 / (1.f + __expf(-c1))) * c3;   // silu(c1)*c3
            grow[16 * j] = (__bf16)g;
          }
        } else {
          int tok = slot_token[slot];
          float w = slot_w[slot];
          float* yrow = Yout + (size_t)tok * N + n0 + wn + ln;
#pragma unroll
          for (int j = 0; j < 4; j++) {
            float v = w * acc1[i][j][r];
            if (ATOMIC) atomicAdd(yrow + 16 * j, v);
            else        yrow[16 * j] = v;
          }
        }
      }
    }
  }
}

// ---------------------------------------------------------------------------
extern "C" void kernel_launch(void* const* d_in, const int* in_sizes, int n_in,
                              void* d_out, int out_size, void* d_ws, size_t ws_size,
                              hipStream_t stream) {
  const float* h   = (const float*)d_in[0];
  const float* sw1 = (const float*)d_in[1];
  const float* sw2 = (const float*)d_in[2];
  const float* sw3 = (const float*)d_in[3];
  const float* W1  = (const float*)d_in[4];
  const float* W2  = (const float*)d_in[5];
  const float* W3  = (const float*)d_in[6];
  const float* Wg  = (const float*)d_in[7];
  float* y = (float*)d_out;

  char* ws = (char*)d_ws;
  int*   meta       = (int*)ws;                              // 256 B
  int*   top_e      = (int*)(ws + 256);                      // 64 KB
  float* top_w      = (float*)(ws + 256 + 65536);            // 64 KB
  int*   slot_token = (int*)(ws + 256 + 131072);             // 96 KB
  float* slot_w     = (float*)(ws + 256 + 131072 + 98304);   // 96 KB
  int4*  table      = (int4*)(ws + 256 + 131072 + 196608);   // 3.2 KB
  size_t off = 0x60000;
  __bf16* h_bf = (__bf16*)(ws + off); off += (size_t)T_TOK * DDIM * 2;      // 16 MB
  __bf16* w1c  = (__bf16*)(ws + off); off += (size_t)9 * HDIM * DDIM * 2;   // 37.75 MB
  __bf16* w3c  = (__bf16*)(ws + off); off += (size_t)9 * HDIM * DDIM * 2;
  __bf16* w2c  = (__bf16*)(ws + off); off += (size_t)9 * DDIM * HDIM * 2;
  __bf16* G    = (__bf16*)(ws + off); off += (size_t)NSLOT * HDIM * 2;      // 100.7 MB
  // total ~231 MB of ws used

  hipMemsetAsync(meta, 0, 256, stream);

  auto cvt = [&](const float* s, __bf16* d, long n) {
    int n4 = (int)(n >> 2);
    cvt_f32_bf16<<<(n4 + 255) / 256, 256, 0, stream>>>(s, d, n4);
  };
  const size_t WB = (size_t)HDIM * DDIM;   // per-expert weight block elems
  cvt(h,   h_bf,            (long)T_TOK * DDIM);
  cvt(W1,  w1c,             (long)NEXP * WB);
  cvt(sw1, w1c + NEXP * WB, (long)WB);
  cvt(W3,  w3c,             (long)NEXP * WB);
  cvt(sw3, w3c + NEXP * WB, (long)WB);
  cvt(W2,  w2c,             (long)NEXP * WB);
  cvt(sw2, w2c + NEXP * WB, (long)WB);

  gate_kernel<<<T_TOK / 4, 256, 0, stream>>>(h, Wg, top_e, top_w, meta);
  build_meta<<<1, 64, 0, stream>>>(meta, table);
  scatter_kernel<<<T_TOK / 256, 256, 0, stream>>>(top_e, top_w, meta, slot_token, slot_w);

  // G = silu(A W1^T) * (A W3^T) for all 24576 slots (shared + routed)
  moe_gemm<true, false><<<dim3(MAX_TILES, HDIM / 128), 256, 0, stream>>>(
      h_bf, w1c, w3c, table, slot_token, nullptr, G, nullptr, DDIM, HDIM);
  // y = G W2^T : shared tiles (table[0..64)) plain-store first...
  moe_gemm<false, false><<<dim3(64, DDIM / 128), 256, 0, stream>>>(
      G, w2c, nullptr, table, slot_token, slot_w, nullptr, y, HDIM, DDIM);
  // ...then routed tiles (table[64..]) atomically accumulate
  moe_gemm<false, true><<<dim3(MAX_TILES - 64, DDIM / 128), 256, 0, stream>>>(
      G, w2c, nullptr, table + 64, slot_token, slot_w, nullptr, y, HDIM, DDIM);
}

// Round 2
// 1113.989 us; speedup vs baseline: 1.0385x; 1.0385x over previous
//
#include <hip/hip_runtime.h>

// ---------------------------------------------------------------------------
// MoE FFN (SwiGLU, top-2 of 8 + shared expert), MI355X gfx950.
// Grouped-GEMM, bf16 MFMA 16x16x32, fp32 acc, fp32-exact routing.
// R2: 8-wave blocks (16 waves/CU), 256-row tiles in gemm2, no atomics
//     (per-slot y_slot + combine kernel).
// ---------------------------------------------------------------------------

#define T_TOK 8192
#define DDIM  1024
#define HDIM  2048
#define NEXP  8
#define NSLOT 24576        // 2*T routed + T shared
#define NROUTED 16384      // always exactly 2*T
#define MAX_T1 200         // 128-row tiles: 64 shared + <=136 routed
#define MAX_T2 112         // 256-row tiles: 32 shared + <=72 routed

typedef __attribute__((ext_vector_type(8))) __bf16 bf16x8;
typedef __attribute__((ext_vector_type(4))) __bf16 bf16x4;
typedef __attribute__((ext_vector_type(4))) float  f32x4;

__device__ __forceinline__ void gload16(const void* g, void* l) {
  __builtin_amdgcn_global_load_lds(
      (const __attribute__((address_space(1))) void*)g,
      (__attribute__((address_space(3))) void*)l, 16, 0, 0);
}

// ---------------- fp32 -> bf16 convert (vector x4) -------------------------
__global__ __launch_bounds__(256) void cvt_f32_bf16(
    const float* __restrict__ s, __bf16* __restrict__ d, int n4) {
  int i = blockIdx.x * 256 + threadIdx.x;
  if (i >= n4) return;
  f32x4 v = ((const f32x4*)s)[i];
  bf16x4 o;
  o[0] = (__bf16)v[0]; o[1] = (__bf16)v[1];
  o[2] = (__bf16)v[2]; o[3] = (__bf16)v[3];
  ((bf16x4*)d)[i] = o;
}

// ---------------- gate: softmax -> top2 -> renorm (fp32 exact) -------------
__global__ __launch_bounds__(256) void gate_kernel(
    const float* __restrict__ h, const float* __restrict__ Wg,
    int* __restrict__ top_e, float* __restrict__ top_w, int* __restrict__ counts) {
  int wv = threadIdx.x >> 6, lane = threadIdx.x & 63;
  int t = blockIdx.x * 4 + wv;
  const float* x = h + (size_t)t * DDIM;
  float acc[NEXP];
#pragma unroll
  for (int e = 0; e < NEXP; e++) acc[e] = 0.f;
  for (int i = lane; i < DDIM; i += 64) {
    float xv = x[i];
#pragma unroll
    for (int e = 0; e < NEXP; e++) acc[e] = fmaf(xv, Wg[e * DDIM + i], acc[e]);
  }
#pragma unroll
  for (int e = 0; e < NEXP; e++) {
#pragma unroll
    for (int off = 32; off > 0; off >>= 1) acc[e] += __shfl_xor(acc[e], off);
  }
  if (lane == 0) {
    int i1 = 0; float v1 = acc[0];
#pragma unroll
    for (int e = 1; e < NEXP; e++) if (acc[e] > v1) { v1 = acc[e]; i1 = e; }
    int i2 = -1; float v2 = -1e30f;
#pragma unroll
    for (int e = 0; e < NEXP; e++) if (e != i1 && acc[e] > v2) { v2 = acc[e]; i2 = e; }
    float e2 = __expf(v2 - v1);
    float w1 = 1.f / (1.f + e2);          // renormalized top-2 weights
    top_e[2 * t] = i1; top_e[2 * t + 1] = i2;
    top_w[2 * t] = w1; top_w[2 * t + 1] = e2 * w1;
    atomicAdd(&counts[i1], 1);
    atomicAdd(&counts[i2], 1);
  }
}

// ---------------- offsets + both tile tables -------------------------------
// meta ints: counts@0, cursor@16, offsets@32
__global__ void build_meta(int* __restrict__ meta, int4* __restrict__ table1,
                           int4* __restrict__ table2) {
  if (threadIdx.x != 0) return;
  int* counts = meta; int* cursor = meta + 16; int* offsets = meta + 32;
  int off = 0;
  for (int e = 0; e < NEXP; e++) { offsets[e] = off; off += counts[e]; cursor[e] = 0; }
  // off == NROUTED always; shared slots follow at [NROUTED, NROUTED+T)
  int nt = 0;
  for (int lt = 0; lt < T_TOK / 128; lt++)
    table1[nt++] = make_int4(NEXP, NROUTED + lt * 128, 128, 0);
  for (int e = 0; e < NEXP; e++) {
    int c = counts[e], s = offsets[e];
    for (int lt = 0; lt * 128 < c; lt++)
      table1[nt++] = make_int4(e, s + lt * 128, min(128, c - lt * 128), 0);
  }
  for (; nt < MAX_T1; nt++) table1[nt] = make_int4(-1, 0, 0, 0);
  nt = 0;
  for (int lt = 0; lt < T_TOK / 256; lt++)
    table2[nt++] = make_int4(NEXP, NROUTED + lt * 256, 256, 0);
  for (int e = 0; e < NEXP; e++) {
    int c = counts[e], s = offsets[e];
    for (int lt = 0; lt * 256 < c; lt++)
      table2[nt++] = make_int4(e, s + lt * 256, min(256, c - lt * 256), 0);
  }
  for (; nt < MAX_T2; nt++) table2[nt] = make_int4(-1, 0, 0, 0);
}

// ---------------- scatter tokens into per-expert slot lists ----------------
__global__ __launch_bounds__(256) void scatter_kernel(
    const int* __restrict__ top_e, const float* __restrict__ top_w,
    int* __restrict__ meta, int* __restrict__ slot_token, float* __restrict__ slot_w,
    int* __restrict__ slot_pos) {
  int t = blockIdx.x * 256 + threadIdx.x;
  int* cursor = meta + 16; const int* offsets = meta + 32;
#pragma unroll
  for (int k = 0; k < 2; k++) {
    int e = top_e[2 * t + k];
    int pos = offsets[e] + atomicAdd(&cursor[e], 1);
    slot_token[pos] = t; slot_w[pos] = top_w[2 * t + k];
    slot_pos[2 * t + k] = pos;
  }
  slot_token[NROUTED + t] = t;           // shared-expert slot
}

// ---------------- GEMM1 (dual): G = silu(A W1^T) * (A W3^T) ---------------
// block 128m x 128n x K=1024, 512 thr (8 waves of 64m x 32n).
// A gathered by slot_token. XOR-chunk-swizzled LDS (conflict-free b128 reads,
// contiguous global_load_lds destinations).
__global__ __launch_bounds__(512, 4) void gemm1_dual(
    const __bf16* __restrict__ Abase, const __bf16* __restrict__ B1base,
    const __bf16* __restrict__ B3base, const int4* __restrict__ table,
    const int* __restrict__ slot_token, __bf16* __restrict__ Gout) {
  const int K = DDIM, N = HDIM;
  int4 te = table[blockIdx.x];
  if (te.x < 0) return;
  const int expert = te.x, slot0 = te.y, rows = te.z;
  const int n0 = blockIdx.y * 128;
  const int tid = threadIdx.x, lane = tid & 63, wave = tid >> 6;
  const int wm = (wave & 1) * 64, wn = (wave >> 1) * 32;

  __shared__ __align__(16) unsigned char lds[49152];

  const int sub = tid >> 3, pc = tid & 7;
  const __bf16* B1 = B1base + (size_t)expert * N * K;
  const __bf16* B3 = B3base + (size_t)expert * N * K;
  const __bf16* aptr[2]; const __bf16* b1p[2]; const __bf16* b3p[2];
#pragma unroll
  for (int i = 0; i < 2; i++) {
    int r = 64 * i + sub;
    int rr = min(r, rows - 1);
    size_t arow = (size_t)slot_token[slot0 + rr];
    int koff = ((pc ^ (r & 7)) << 3);
    aptr[i] = Abase + arow * (size_t)K + koff;
    b1p[i] = B1 + (size_t)(n0 + r) * K + koff;
    b3p[i] = B3 + (size_t)(n0 + r) * K + koff;
  }

  f32x4 acc1[4][2] = {};
  f32x4 acc3[4][2] = {};
  const int q = lane >> 4, ln = lane & 15;

  for (int k0 = 0; k0 < K; k0 += 64) {
#pragma unroll
    for (int i = 0; i < 2; i++) {
      gload16(aptr[i] + k0, lds + i * 8192 + wave * 1024);
      gload16(b1p[i] + k0, lds + 16384 + i * 8192 + wave * 1024);
      gload16(b3p[i] + k0, lds + 32768 + i * 8192 + wave * 1024);
    }
    __syncthreads();
#pragma unroll
    for (int ks = 0; ks < 2; ks++) {
      bf16x8 af[4], b1f[2], b3f[2];
#pragma unroll
      for (int i = 0; i < 4; i++) {
        int row = wm + 16 * i + ln;
        af[i] = *(const bf16x8*)(lds + ((row * 8 + ((ks * 4 + q) ^ (row & 7))) << 4));
      }
#pragma unroll
      for (int j = 0; j < 2; j++) {
        int col = wn + 16 * j + ln;
        b1f[j] = *(const bf16x8*)(lds + 16384 + ((col * 8 + ((ks * 4 + q) ^ (col & 7))) << 4));
        b3f[j] = *(const bf16x8*)(lds + 32768 + ((col * 8 + ((ks * 4 + q) ^ (col & 7))) << 4));
      }
#pragma unroll
      for (int i = 0; i < 4; i++) {
#pragma unroll
        for (int j = 0; j < 2; j++) {
          acc1[i][j] = __builtin_amdgcn_mfma_f32_16x16x32_bf16(af[i], b1f[j], acc1[i][j], 0, 0, 0);
          acc3[i][j] = __builtin_amdgcn_mfma_f32_16x16x32_bf16(af[i], b3f[j], acc3[i][j], 0, 0, 0);
        }
      }
    }
    __syncthreads();
  }

  // epilogue: C/D layout col=lane&15, row=(lane>>4)*4+reg
#pragma unroll
  for (int i = 0; i < 4; i++) {
#pragma unroll
    for (int r = 0; r < 4; r++) {
      int m = wm + 16 * i + q * 4 + r;
      if (m < rows) {
        __bf16* grow = Gout + (size_t)(slot0 + m) * N + n0 + wn + ln;
#pragma unroll
        for (int j = 0; j < 2; j++) {
          float c1 = acc1[i][j][r], c3 = acc3[i][j][r];
          float g = (c1 / (1.f + __expf(-c1))) * c3;
          grow[16 * j] = (__bf16)g;
        }
      }
    }
  }
}

// ---------------- GEMM2: y_slot = G W2^T (per-slot, plain stores) ----------
// block 256m x 128n x K=2048, 512 thr (8 waves of 64m x 64n). A contiguous.
__global__ __launch_bounds__(512, 4) void gemm2_single(
    const __bf16* __restrict__ Abase, const __bf16* __restrict__ Bbase,
    const int4* __restrict__ table, __bf16* __restrict__ ys) {
  const int K = HDIM, N = DDIM;
  int4 te = table[blockIdx.x];
  if (te.x < 0) return;
  const int expert = te.x, slot0 = te.y, rows = te.z;
  const int n0 = blockIdx.y * 128;
  const int tid = threadIdx.x, lane = tid & 63, wave = tid >> 6;
  const int wm = (wave & 3) * 64, wn = (wave >> 2) * 64;

  __shared__ __align__(16) unsigned char lds[49152];   // A 32K | B 16K

  const int sub = tid >> 3, pc = tid & 7;
  const __bf16* B = Bbase + (size_t)expert * N * K;
  const __bf16* aptr[4]; const __bf16* bp[2];
#pragma unroll
  for (int i = 0; i < 4; i++) {
    int r = 64 * i + sub;
    int rr = min(r, rows - 1);
    int koff = ((pc ^ (r & 7)) << 3);
    aptr[i] = Abase + (size_t)(slot0 + rr) * K + koff;
  }
#pragma unroll
  for (int i = 0; i < 2; i++) {
    int r = 64 * i + sub;
    int koff = ((pc ^ (r & 7)) << 3);
    bp[i] = B + (size_t)(n0 + r) * K + koff;
  }

  f32x4 acc[4][4] = {};
  const int q = lane >> 4, ln = lane & 15;

  for (int k0 = 0; k0 < K; k0 += 64) {
#pragma unroll
    for (int i = 0; i < 4; i++)
      gload16(aptr[i] + k0, lds + i * 8192 + wave * 1024);
#pragma unroll
    for (int i = 0; i < 2; i++)
      gload16(bp[i] + k0, lds + 32768 + i * 8192 + wave * 1024);
    __syncthreads();
#pragma unroll
    for (int ks = 0; ks < 2; ks++) {
      bf16x8 af[4], bf[4];
#pragma unroll
      for (int i = 0; i < 4; i++) {
        int row = wm + 16 * i + ln;
        af[i] = *(const bf16x8*)(lds + ((row * 8 + ((ks * 4 + q) ^ (row & 7))) << 4));
        int col = wn + 16 * i + ln;
        bf[i] = *(const bf16x8*)(lds + 32768 + ((col * 8 + ((ks * 4 + q) ^ (col & 7))) << 4));
      }
#pragma unroll
      for (int i = 0; i < 4; i++) {
#pragma unroll
        for (int j = 0; j < 4; j++)
          acc[i][j] = __builtin_amdgcn_mfma_f32_16x16x32_bf16(af[i], bf[j], acc[i][j], 0, 0, 0);
      }
    }
    __syncthreads();
  }

#pragma unroll
  for (int i = 0; i < 4; i++) {
#pragma unroll
    for (int r = 0; r < 4; r++) {
      int m = wm + 16 * i + q * 4 + r;
      if (m < rows) {
        __bf16* yrow = ys + (size_t)(slot0 + m) * N + n0 + wn + ln;
#pragma unroll
        for (int j = 0; j < 4; j++)
          yrow[16 * j] = (__bf16)acc[i][j][r];
      }
    }
  }
}

// ---------------- combine: y[t] = w1*ys[p1] + w2*ys[p2] + ys[shared] -------
__global__ __launch_bounds__(256) void combine_kernel(
    const __bf16* __restrict__ ys, const int* __restrict__ slot_pos,
    const float* __restrict__ slot_w, float* __restrict__ y) {
  int t = blockIdx.x, d = threadIdx.x * 4;
  int p1 = slot_pos[2 * t], p2 = slot_pos[2 * t + 1];
  float w1 = slot_w[p1], w2 = slot_w[p2];
  bf16x4 a = *(const bf16x4*)(ys + (size_t)p1 * DDIM + d);
  bf16x4 b = *(const bf16x4*)(ys + (size_t)p2 * DDIM + d);
  bf16x4 c = *(const bf16x4*)(ys + (size_t)(NROUTED + t) * DDIM + d);
  f32x4 o;
#pragma unroll
  for (int i = 0; i < 4; i++)
    o[i] = fmaf(w1, (float)a[i], fmaf(w2, (float)b[i], (float)c[i]));
  *(f32x4*)(y + (size_t)t * DDIM + d) = o;
}

// ---------------------------------------------------------------------------
extern "C" void kernel_launch(void* const* d_in, const int* in_sizes, int n_in,
                              void* d_out, int out_size, void* d_ws, size_t ws_size,
                              hipStream_t stream) {
  const float* h   = (const float*)d_in[0];
  const float* sw1 = (const float*)d_in[1];
  const float* sw2 = (const float*)d_in[2];
  const float* sw3 = (const float*)d_in[3];
  const float* W1  = (const float*)d_in[4];
  const float* W2  = (const float*)d_in[5];
  const float* W3  = (const float*)d_in[6];
  const float* Wg  = (const float*)d_in[7];
  float* y = (float*)d_out;

  char* ws = (char*)d_ws;
  int*   meta       = (int*)ws;                               // 256 B
  int*   top_e      = (int*)(ws + 256);                       // 64 KB
  float* top_w      = (float*)(ws + 256 + 65536);             // 64 KB
  int*   slot_token = (int*)(ws + 256 + 131072);              // 96 KB
  float* slot_w     = (float*)(ws + 256 + 131072 + 98304);    // 96 KB
  int*   slot_pos   = (int*)(ws + 256 + 131072 + 196608);     // 64 KB
  int4*  table1     = (int4*)(ws + 256 + 131072 + 262144);    // 3.2 KB
  int4*  table2     = (int4*)(ws + 256 + 131072 + 262144 + 4096);
  size_t off = 0x80000;
  __bf16* h_bf = (__bf16*)(ws + off); off += (size_t)T_TOK * DDIM * 2;      // 16 MB
  size_t w13_off = off;                                                     // w1c+w3c region
  __bf16* w1c  = (__bf16*)(ws + off); off += (size_t)9 * HDIM * DDIM * 2;   // 37.75 MB
  __bf16* w3c  = (__bf16*)(ws + off); off += (size_t)9 * HDIM * DDIM * 2;   // 37.75 MB
  __bf16* w2c  = (__bf16*)(ws + off); off += (size_t)9 * DDIM * HDIM * 2;   // 37.75 MB
  __bf16* G    = (__bf16*)(ws + off); off += (size_t)NSLOT * HDIM * 2;      // 100.7 MB
  // y_slot overlays w1c/w3c (dead after gemm1): 24576*1024*2 = 50.3 MB < 75.5 MB
  __bf16* yslot = (__bf16*)(ws + w13_off);

  hipMemsetAsync(meta, 0, 256, stream);

  auto cvt = [&](const float* s, __bf16* d, long n) {
    int n4 = (int)(n >> 2);
    cvt_f32_bf16<<<(n4 + 255) / 256, 256, 0, stream>>>(s, d, n4);
  };
  const size_t WB = (size_t)HDIM * DDIM;
  cvt(h,   h_bf,            (long)T_TOK * DDIM);
  cvt(W1,  w1c,             (long)NEXP * WB);
  cvt(sw1, w1c + NEXP * WB, (long)WB);
  cvt(W3,  w3c,             (long)NEXP * WB);
  cvt(sw3, w3c + NEXP * WB, (long)WB);
  cvt(W2,  w2c,             (long)NEXP * WB);
  cvt(sw2, w2c + NEXP * WB, (long)WB);

  gate_kernel<<<T_TOK / 4, 256, 0, stream>>>(h, Wg, top_e, top_w, meta);
  build_meta<<<1, 64, 0, stream>>>(meta, table1, table2);
  scatter_kernel<<<T_TOK / 256, 256, 0, stream>>>(top_e, top_w, meta,
                                                  slot_token, slot_w, slot_pos);

  gemm1_dual<<<dim3(MAX_T1, HDIM / 128), 512, 0, stream>>>(
      h_bf, w1c, w3c, table1, slot_token, G);
  gemm2_single<<<dim3(MAX_T2, DDIM / 128), 512, 0, stream>>>(
      G, w2c, table2, yslot);
  combine_kernel<<<T_TOK, 256, 0, stream>>>(yslot, slot_pos, slot_w, y);
}

// Round 3
// 1002.466 us; speedup vs baseline: 1.1541x; 1.1112x over previous
//
#include <hip/hip_runtime.h>

// ---------------------------------------------------------------------------
// MoE FFN (SwiGLU, top-2 of 8 + shared expert), MI355X gfx950.
// Grouped-GEMM, bf16 MFMA 16x16x32, fp32 acc, fp32-exact routing.
// R3: vectorized 16B epilogue stores (LDS transpose, wave-local),
//     XCD-aware grid swizzle for B-tile L2 locality,
//     ballot-ordered scatter for A-gather locality.
// ---------------------------------------------------------------------------

#define T_TOK 8192
#define DDIM  1024
#define HDIM  2048
#define NEXP  8
#define NSLOT 24576        // 2*T routed + T shared
#define NROUTED 16384      // always exactly 2*T
#define MAX_T1 200         // 128-row tiles: 64 shared + <=136 routed
#define MAX_T2 112         // 256-row tiles: 32 shared + <=72 routed

typedef __attribute__((ext_vector_type(8))) __bf16 bf16x8;
typedef __attribute__((ext_vector_type(4))) __bf16 bf16x4;
typedef __attribute__((ext_vector_type(4))) float  f32x4;

__device__ __forceinline__ void gload16(const void* g, void* l) {
  __builtin_amdgcn_global_load_lds(
      (const __attribute__((address_space(1))) void*)g,
      (__attribute__((address_space(3))) void*)l, 16, 0, 0);
}

#define LDS_FENCE() __asm__ __volatile__("s_waitcnt lgkmcnt(0)" ::: "memory")

// ---------------- fp32 -> bf16 convert (vector x4) -------------------------
__global__ __launch_bounds__(256) void cvt_f32_bf16(
    const float* __restrict__ s, __bf16* __restrict__ d, int n4) {
  int i = blockIdx.x * 256 + threadIdx.x;
  if (i >= n4) return;
  f32x4 v = ((const f32x4*)s)[i];
  bf16x4 o;
  o[0] = (__bf16)v[0]; o[1] = (__bf16)v[1];
  o[2] = (__bf16)v[2]; o[3] = (__bf16)v[3];
  ((bf16x4*)d)[i] = o;
}

// ---------------- gate: softmax -> top2 -> renorm (fp32 exact) -------------
__global__ __launch_bounds__(256) void gate_kernel(
    const float* __restrict__ h, const float* __restrict__ Wg,
    int* __restrict__ top_e, float* __restrict__ top_w, int* __restrict__ counts) {
  int wv = threadIdx.x >> 6, lane = threadIdx.x & 63;
  int t = blockIdx.x * 4 + wv;
  const float* x = h + (size_t)t * DDIM;
  float acc[NEXP];
#pragma unroll
  for (int e = 0; e < NEXP; e++) acc[e] = 0.f;
  for (int i = lane; i < DDIM; i += 64) {
    float xv = x[i];
#pragma unroll
    for (int e = 0; e < NEXP; e++) acc[e] = fmaf(xv, Wg[e * DDIM + i], acc[e]);
  }
#pragma unroll
  for (int e = 0; e < NEXP; e++) {
#pragma unroll
    for (int off = 32; off > 0; off >>= 1) acc[e] += __shfl_xor(acc[e], off);
  }
  if (lane == 0) {
    int i1 = 0; float v1 = acc[0];
#pragma unroll
    for (int e = 1; e < NEXP; e++) if (acc[e] > v1) { v1 = acc[e]; i1 = e; }
    int i2 = -1; float v2 = -1e30f;
#pragma unroll
    for (int e = 0; e < NEXP; e++) if (e != i1 && acc[e] > v2) { v2 = acc[e]; i2 = e; }
    float e2 = __expf(v2 - v1);
    float w1 = 1.f / (1.f + e2);          // renormalized top-2 weights
    top_e[2 * t] = i1; top_e[2 * t + 1] = i2;
    top_w[2 * t] = w1; top_w[2 * t + 1] = e2 * w1;
    atomicAdd(&counts[i1], 1);
    atomicAdd(&counts[i2], 1);
  }
}

// ---------------- offsets + both tile tables -------------------------------
// meta ints: counts@0, cursor@16, offsets@32
__global__ void build_meta(int* __restrict__ meta, int4* __restrict__ table1,
                           int4* __restrict__ table2) {
  if (threadIdx.x != 0) return;
  int* counts = meta; int* cursor = meta + 16; int* offsets = meta + 32;
  int off = 0;
  for (int e = 0; e < NEXP; e++) { offsets[e] = off; off += counts[e]; cursor[e] = 0; }
  int nt = 0;
  for (int lt = 0; lt < T_TOK / 128; lt++)
    table1[nt++] = make_int4(NEXP, NROUTED + lt * 128, 128, 0);
  for (int e = 0; e < NEXP; e++) {
    int c = counts[e], s = offsets[e];
    for (int lt = 0; lt * 128 < c; lt++)
      table1[nt++] = make_int4(e, s + lt * 128, min(128, c - lt * 128), 0);
  }
  for (; nt < MAX_T1; nt++) table1[nt] = make_int4(-1, 0, 0, 0);
  nt = 0;
  for (int lt = 0; lt < T_TOK / 256; lt++)
    table2[nt++] = make_int4(NEXP, NROUTED + lt * 256, 256, 0);
  for (int e = 0; e < NEXP; e++) {
    int c = counts[e], s = offsets[e];
    for (int lt = 0; lt * 256 < c; lt++)
      table2[nt++] = make_int4(e, s + lt * 256, min(256, c - lt * 256), 0);
  }
  for (; nt < MAX_T2; nt++) table2[nt] = make_int4(-1, 0, 0, 0);
}

// ---------------- scatter: ballot-ordered per-expert slot lists ------------
// 64-token wave windows stay contiguous in slot space -> A-gather locality.
__global__ __launch_bounds__(256) void scatter_kernel(
    const int* __restrict__ top_e, const float* __restrict__ top_w,
    int* __restrict__ meta, int* __restrict__ slot_token, float* __restrict__ slot_w,
    int* __restrict__ slot_pos) {
  int t = blockIdx.x * 256 + threadIdx.x;
  int lane = threadIdx.x & 63;
  int* cursor = meta + 16; const int* offsets = meta + 32;
#pragma unroll
  for (int k = 0; k < 2; k++) {
    int e = top_e[2 * t + k];
    unsigned long long same = 0;
#pragma unroll
    for (int ee = 0; ee < NEXP; ee++) {
      unsigned long long m = __ballot(e == ee);
      if (ee == e) same = m;
    }
    int leader = __ffsll((long long)same) - 1;
    int base = 0;
    if (lane == leader) base = atomicAdd(&cursor[e], __popcll(same));
    base = __shfl(base, leader);
    int pos = offsets[e] + base + (int)__popcll(same & ((1ull << lane) - 1ull));
    slot_token[pos] = t; slot_w[pos] = top_w[2 * t + k];
    slot_pos[2 * t + k] = pos;
  }
  slot_token[NROUTED + t] = t;           // shared-expert slot
}

// ---------------- GEMM1 (dual): G = silu(A W1^T) * (A W3^T) ---------------
// block 128m x 128n x K=1024, 512 thr (8 waves of 64m x 32n).
// Grid: 1D, xcd = b&7 owns nblocks {xcd, xcd+8}; tiles walked in expert order
// so the live B working set per XCD L2 is ~1 MB.
__global__ __launch_bounds__(512, 4) void gemm1_dual(
    const __bf16* __restrict__ Abase, const __bf16* __restrict__ B1base,
    const __bf16* __restrict__ B3base, const int4* __restrict__ table,
    const int* __restrict__ slot_token, __bf16* __restrict__ Gout) {
  const int K = DDIM, N = HDIM;
  int b = blockIdx.x;
  int j0 = b >> 3;
  int tile = j0 % MAX_T1;
  int nbk = (b & 7) + 8 * (j0 / MAX_T1);
  int4 te = table[tile];
  if (te.x < 0) return;
  const int expert = te.x, slot0 = te.y, rows = te.z;
  const int n0 = nbk * 128;
  const int tid = threadIdx.x, lane = tid & 63, wave = tid >> 6;
  const int wm = (wave & 1) * 64, wn = (wave >> 1) * 32;

  __shared__ __align__(16) unsigned char lds[49152];

  const int sub = tid >> 3, pc = tid & 7;
  const __bf16* B1 = B1base + (size_t)expert * N * K;
  const __bf16* B3 = B3base + (size_t)expert * N * K;
  const __bf16* aptr[2]; const __bf16* b1p[2]; const __bf16* b3p[2];
#pragma unroll
  for (int i = 0; i < 2; i++) {
    int r = 64 * i + sub;
    int rr = min(r, rows - 1);
    size_t arow = (size_t)slot_token[slot0 + rr];
    int koff = ((pc ^ (r & 7)) << 3);
    aptr[i] = Abase + arow * (size_t)K + koff;
    b1p[i] = B1 + (size_t)(n0 + r) * K + koff;
    b3p[i] = B3 + (size_t)(n0 + r) * K + koff;
  }

  f32x4 acc1[4][2] = {};
  f32x4 acc3[4][2] = {};
  const int q = lane >> 4, ln = lane & 15;

  for (int k0 = 0; k0 < K; k0 += 64) {
#pragma unroll
    for (int i = 0; i < 2; i++) {
      gload16(aptr[i] + k0, lds + i * 8192 + wave * 1024);
      gload16(b1p[i] + k0, lds + 16384 + i * 8192 + wave * 1024);
      gload16(b3p[i] + k0, lds + 32768 + i * 8192 + wave * 1024);
    }
    __syncthreads();
#pragma unroll
    for (int ks = 0; ks < 2; ks++) {
      bf16x8 af[4], b1f[2], b3f[2];
#pragma unroll
      for (int i = 0; i < 4; i++) {
        int row = wm + 16 * i + ln;
        af[i] = *(const bf16x8*)(lds + ((row * 8 + ((ks * 4 + q) ^ (row & 7))) << 4));
      }
#pragma unroll
      for (int jj = 0; jj < 2; jj++) {
        int col = wn + 16 * jj + ln;
        b1f[jj] = *(const bf16x8*)(lds + 16384 + ((col * 8 + ((ks * 4 + q) ^ (col & 7))) << 4));
        b3f[jj] = *(const bf16x8*)(lds + 32768 + ((col * 8 + ((ks * 4 + q) ^ (col & 7))) << 4));
      }
#pragma unroll
      for (int i = 0; i < 4; i++) {
#pragma unroll
        for (int jj = 0; jj < 2; jj++) {
          acc1[i][jj] = __builtin_amdgcn_mfma_f32_16x16x32_bf16(af[i], b1f[jj], acc1[i][jj], 0, 0, 0);
          acc3[i][jj] = __builtin_amdgcn_mfma_f32_16x16x32_bf16(af[i], b3f[jj], acc3[i][jj], 0, 0, 0);
        }
      }
    }
    __syncthreads();
  }

  // ---- epilogue: silu-combine -> wave-local LDS transpose -> 16B stores
  // wbuf: 64 rows x stride 36 bf16 per wave (4608 B x 8 waves = 36.8 KB)
  __bf16* wbuf = (__bf16*)lds + wave * (64 * 36);
#pragma unroll
  for (int i = 0; i < 4; i++) {
#pragma unroll
    for (int jj = 0; jj < 2; jj++) {
#pragma unroll
      for (int r = 0; r < 4; r++) {
        float c1 = acc1[i][jj][r], c3 = acc3[i][jj][r];
        float g = (c1 / (1.f + __expf(-c1))) * c3;
        wbuf[(16 * i + 4 * q + r) * 36 + 16 * jj + ln] = (__bf16)g;
      }
    }
  }
  LDS_FENCE();
#pragma unroll
  for (int i2 = 0; i2 < 4; i2++) {
    int m = i2 * 16 + (lane >> 2);
    int n = (lane & 3) * 8;
    if (wm + m < rows) {
      bf16x8 v = *(const bf16x8*)(wbuf + m * 36 + n);
      *(bf16x8*)(Gout + (size_t)(slot0 + wm + m) * N + n0 + wn + n) = v;
    }
  }
}

// ---------------- GEMM2: y_slot = G W2^T (per-slot, plain stores) ----------
// block 256m x 128n x K=2048, 512 thr (8 waves of 64m x 64n). A contiguous.
// Grid: xcd = b&7 = nblock (fixed per XCD), tiles walked in expert order.
__global__ __launch_bounds__(512, 4) void gemm2_single(
    const __bf16* __restrict__ Abase, const __bf16* __restrict__ Bbase,
    const int4* __restrict__ table, __bf16* __restrict__ ys) {
  const int K = HDIM, N = DDIM;
  int b = blockIdx.x;
  int tile = b >> 3, nbk = b & 7;
  int4 te = table[tile];
  if (te.x < 0) return;
  const int expert = te.x, slot0 = te.y, rows = te.z;
  const int n0 = nbk * 128;
  const int tid = threadIdx.x, lane = tid & 63, wave = tid >> 6;
  const int wm = (wave & 3) * 64, wn = (wave >> 2) * 64;

  __shared__ __align__(16) unsigned char lds[49152];   // A 32K | B 16K

  const int sub = tid >> 3, pc = tid & 7;
  const __bf16* B = Bbase + (size_t)expert * N * K;
  const __bf16* aptr[4]; const __bf16* bp[2];
#pragma unroll
  for (int i = 0; i < 4; i++) {
    int r = 64 * i + sub;
    int rr = min(r, rows - 1);
    int koff = ((pc ^ (r & 7)) << 3);
    aptr[i] = Abase + (size_t)(slot0 + rr) * K + koff;
  }
#pragma unroll
  for (int i = 0; i < 2; i++) {
    int r = 64 * i + sub;
    int koff = ((pc ^ (r & 7)) << 3);
    bp[i] = B + (size_t)(n0 + r) * K + koff;
  }

  f32x4 acc[4][4] = {};
  const int q = lane >> 4, ln = lane & 15;

  for (int k0 = 0; k0 < K; k0 += 64) {
#pragma unroll
    for (int i = 0; i < 4; i++)
      gload16(aptr[i] + k0, lds + i * 8192 + wave * 1024);
#pragma unroll
    for (int i = 0; i < 2; i++)
      gload16(bp[i] + k0, lds + 32768 + i * 8192 + wave * 1024);
    __syncthreads();
#pragma unroll
    for (int ks = 0; ks < 2; ks++) {
      bf16x8 af[4], bf[4];
#pragma unroll
      for (int i = 0; i < 4; i++) {
        int row = wm + 16 * i + ln;
        af[i] = *(const bf16x8*)(lds + ((row * 8 + ((ks * 4 + q) ^ (row & 7))) << 4));
        int col = wn + 16 * i + ln;
        bf[i] = *(const bf16x8*)(lds + 32768 + ((col * 8 + ((ks * 4 + q) ^ (col & 7))) << 4));
      }
#pragma unroll
      for (int i = 0; i < 4; i++) {
#pragma unroll
        for (int jj = 0; jj < 4; jj++)
          acc[i][jj] = __builtin_amdgcn_mfma_f32_16x16x32_bf16(af[i], bf[jj], acc[i][jj], 0, 0, 0);
      }
    }
    __syncthreads();
  }

  // ---- epilogue: two 32-col half-passes through wave-local LDS transpose
  __bf16* wbuf = (__bf16*)lds + wave * (64 * 36);
#pragma unroll
  for (int half = 0; half < 2; half++) {
    LDS_FENCE();   // prev half's reads complete before overwrite
#pragma unroll
    for (int i = 0; i < 4; i++) {
#pragma unroll
      for (int jj = 0; jj < 2; jj++) {
#pragma unroll
        for (int r = 0; r < 4; r++)
          wbuf[(16 * i + 4 * q + r) * 36 + 16 * jj + ln] =
              (__bf16)acc[i][half * 2 + jj][r];
      }
    }
    LDS_FENCE();
#pragma unroll
    for (int i2 = 0; i2 < 4; i2++) {
      int m = i2 * 16 + (lane >> 2);
      int n = (lane & 3) * 8;
      if (wm + m < rows) {
        bf16x8 v = *(const bf16x8*)(wbuf + m * 36 + n);
        *(bf16x8*)(ys + (size_t)(slot0 + wm + m) * N + n0 + wn + half * 32 + n) = v;
      }
    }
  }
}

// ---------------- combine: y[t] = w1*ys[p1] + w2*ys[p2] + ys[shared] -------
__global__ __launch_bounds__(256) void combine_kernel(
    const __bf16* __restrict__ ys, const int* __restrict__ slot_pos,
    const float* __restrict__ slot_w, float* __restrict__ y) {
  int t = blockIdx.x, d = threadIdx.x * 4;
  int p1 = slot_pos[2 * t], p2 = slot_pos[2 * t + 1];
  float w1 = slot_w[p1], w2 = slot_w[p2];
  bf16x4 a = *(const bf16x4*)(ys + (size_t)p1 * DDIM + d);
  bf16x4 b = *(const bf16x4*)(ys + (size_t)p2 * DDIM + d);
  bf16x4 c = *(const bf16x4*)(ys + (size_t)(NROUTED + t) * DDIM + d);
  f32x4 o;
#pragma unroll
  for (int i = 0; i < 4; i++)
    o[i] = fmaf(w1, (float)a[i], fmaf(w2, (float)b[i], (float)c[i]));
  *(f32x4*)(y + (size_t)t * DDIM + d) = o;
}

// ---------------------------------------------------------------------------
extern "C" void kernel_launch(void* const* d_in, const int* in_sizes, int n_in,
                              void* d_out, int out_size, void* d_ws, size_t ws_size,
                              hipStream_t stream) {
  const float* h   = (const float*)d_in[0];
  const float* sw1 = (const float*)d_in[1];
  const float* sw2 = (const float*)d_in[2];
  const float* sw3 = (const float*)d_in[3];
  const float* W1  = (const float*)d_in[4];
  const float* W2  = (const float*)d_in[5];
  const float* W3  = (const float*)d_in[6];
  const float* Wg  = (const float*)d_in[7];
  float* y = (float*)d_out;

  char* ws = (char*)d_ws;
  int*   meta       = (int*)ws;                               // 256 B
  int*   top_e      = (int*)(ws + 256);                       // 64 KB
  float* top_w      = (float*)(ws + 256 + 65536);             // 64 KB
  int*   slot_token = (int*)(ws + 256 + 131072);              // 96 KB
  float* slot_w     = (float*)(ws + 256 + 131072 + 98304);    // 96 KB
  int*   slot_pos   = (int*)(ws + 256 + 131072 + 196608);     // 64 KB
  int4*  table1     = (int4*)(ws + 256 + 131072 + 262144);    // 3.2 KB
  int4*  table2     = (int4*)(ws + 256 + 131072 + 262144 + 4096);
  size_t off = 0x80000;
  __bf16* h_bf = (__bf16*)(ws + off); off += (size_t)T_TOK * DDIM * 2;      // 16 MB
  size_t w13_off = off;
  __bf16* w1c  = (__bf16*)(ws + off); off += (size_t)9 * HDIM * DDIM * 2;   // 37.75 MB
  __bf16* w3c  = (__bf16*)(ws + off); off += (size_t)9 * HDIM * DDIM * 2;   // 37.75 MB
  __bf16* w2c  = (__bf16*)(ws + off); off += (size_t)9 * DDIM * HDIM * 2;   // 37.75 MB
  __bf16* G    = (__bf16*)(ws + off); off += (size_t)NSLOT * HDIM * 2;      // 100.7 MB
  // y_slot overlays w1c/w3c (dead after gemm1): 50.3 MB < 75.5 MB
  __bf16* yslot = (__bf16*)(ws + w13_off);

  hipMemsetAsync(meta, 0, 256, stream);

  auto cvt = [&](const float* s, __bf16* d, long n) {
    int n4 = (int)(n >> 2);
    cvt_f32_bf16<<<(n4 + 255) / 256, 256, 0, stream>>>(s, d, n4);
  };
  const size_t WB = (size_t)HDIM * DDIM;
  cvt(h,   h_bf,            (long)T_TOK * DDIM);
  cvt(W1,  w1c,             (long)NEXP * WB);
  cvt(sw1, w1c + NEXP * WB, (long)WB);
  cvt(W3,  w3c,             (long)NEXP * WB);
  cvt(sw3, w3c + NEXP * WB, (long)WB);
  cvt(W2,  w2c,             (long)NEXP * WB);
  cvt(sw2, w2c + NEXP * WB, (long)WB);

  gate_kernel<<<T_TOK / 4, 256, 0, stream>>>(h, Wg, top_e, top_w, meta);
  build_meta<<<1, 64, 0, stream>>>(meta, table1, table2);
  scatter_kernel<<<T_TOK / 256, 256, 0, stream>>>(top_e, top_w, meta,
                                                  slot_token, slot_w, slot_pos);

  gemm1_dual<<<MAX_T1 * (HDIM / 128), 512, 0, stream>>>(
      h_bf, w1c, w3c, table1, slot_token, G);
  gemm2_single<<<MAX_T2 * (DDIM / 128), 512, 0, stream>>>(
      G, w2c, table2, yslot);
  combine_kernel<<<T_TOK, 256, 0, stream>>>(yslot, slot_pos, slot_w, y);
}

// Round 4
// 939.270 us; speedup vs baseline: 1.2317x; 1.0673x over previous
//
#include <hip/hip_runtime.h>

// ---------------------------------------------------------------------------
// MoE FFN (SwiGLU, top-2 of 8 + shared expert), MI355X gfx950.
// Grouped-GEMM, bf16 MFMA 16x16x32, fp32 acc, fp32-exact routing.
// R4: full-line store ownership (32m x 64n wave tiles, 128B store instrs),
//     BK=32 -> 34.8KB LDS -> 4 blocks/CU in both GEMMs,
//     gemm2 on 128-row tiles (grid 1600), fused single cvt kernel.
// ---------------------------------------------------------------------------

#define T_TOK 8192
#define DDIM  1024
#define HDIM  2048
#define NEXP  8
#define NSLOT 24576        // 2*T routed + T shared
#define NROUTED 16384      // always exactly 2*T
#define MAX_T1 200         // 128-row tiles: 64 shared + <=135 routed

typedef __attribute__((ext_vector_type(8))) __bf16 bf16x8;
typedef __attribute__((ext_vector_type(4))) __bf16 bf16x4;
typedef __attribute__((ext_vector_type(4))) float  f32x4;

__device__ __forceinline__ void gload16(const void* g, void* l) {
  __builtin_amdgcn_global_load_lds(
      (const __attribute__((address_space(1))) void*)g,
      (__attribute__((address_space(3))) void*)l, 16, 0, 0);
}

#define LDS_FENCE() __asm__ __volatile__("s_waitcnt lgkmcnt(0)" ::: "memory")

// ---------------- fused fp32 -> bf16 convert (all 7 tensors, 1 launch) -----
struct CvtArgs { const float* s[7]; __bf16* d[7]; };

__global__ __launch_bounds__(256) void cvt_fused(CvtArgs a) {
  // vec4 cumulative bounds: h, W1, sw1, W3, sw3, W2, sw2
  constexpr long cum[8] = {0, 2097152, 6291456, 6815744, 11010048,
                           11534336, 15728640, 16252928};
  long i = (long)blockIdx.x * 256 + threadIdx.x;
  if (i >= cum[7]) return;
  int r = 0;
#pragma unroll
  for (int k = 1; k < 7; k++) if (i >= cum[k]) r = k;
  long o = i - cum[r];
  f32x4 v = ((const f32x4*)a.s[r])[o];
  bf16x4 w;
  w[0] = (__bf16)v[0]; w[1] = (__bf16)v[1];
  w[2] = (__bf16)v[2]; w[3] = (__bf16)v[3];
  ((bf16x4*)a.d[r])[o] = w;
}

// ---------------- gate: softmax -> top2 -> renorm (fp32 exact) -------------
__global__ __launch_bounds__(256) void gate_kernel(
    const float* __restrict__ h, const float* __restrict__ Wg,
    int* __restrict__ top_e, float* __restrict__ top_w, int* __restrict__ counts) {
  int wv = threadIdx.x >> 6, lane = threadIdx.x & 63;
  int t = blockIdx.x * 4 + wv;
  const float* x = h + (size_t)t * DDIM;
  float acc[NEXP];
#pragma unroll
  for (int e = 0; e < NEXP; e++) acc[e] = 0.f;
  for (int i = lane; i < DDIM; i += 64) {
    float xv = x[i];
#pragma unroll
    for (int e = 0; e < NEXP; e++) acc[e] = fmaf(xv, Wg[e * DDIM + i], acc[e]);
  }
#pragma unroll
  for (int e = 0; e < NEXP; e++) {
#pragma unroll
    for (int off = 32; off > 0; off >>= 1) acc[e] += __shfl_xor(acc[e], off);
  }
  if (lane == 0) {
    int i1 = 0; float v1 = acc[0];
#pragma unroll
    for (int e = 1; e < NEXP; e++) if (acc[e] > v1) { v1 = acc[e]; i1 = e; }
    int i2 = -1; float v2 = -1e30f;
#pragma unroll
    for (int e = 0; e < NEXP; e++) if (e != i1 && acc[e] > v2) { v2 = acc[e]; i2 = e; }
    float e2 = __expf(v2 - v1);
    float w1 = 1.f / (1.f + e2);          // renormalized top-2 weights
    top_e[2 * t] = i1; top_e[2 * t + 1] = i2;
    top_w[2 * t] = w1; top_w[2 * t + 1] = e2 * w1;
    atomicAdd(&counts[i1], 1);
    atomicAdd(&counts[i2], 1);
  }
}

// ---------------- offsets + tile table (one wave) --------------------------
// meta ints: counts@0, cursor@16, offsets@32
__global__ void build_meta(int* __restrict__ meta, int4* __restrict__ table1) {
  __shared__ int toff[NEXP + 1];
  int lane = threadIdx.x;
  int* counts = meta; int* cursor = meta + 16; int* offsets = meta + 32;
  if (lane == 0) {
    int off = 0, tf = 64;   // shared tiles occupy [0,64)
    for (int e = 0; e < NEXP; e++) {
      offsets[e] = off; cursor[e] = 0;
      toff[e] = tf;
      tf += (counts[e] + 127) >> 7;
      off += counts[e];
    }
    toff[NEXP] = tf;
  }
  __syncthreads();
  for (int i = lane; i < MAX_T1; i += 64) {
    if (i < 64) {
      table1[i] = make_int4(NEXP, NROUTED + i * 128, 128, 0);
    } else if (i < toff[NEXP]) {
      int e = 0;
#pragma unroll
      for (int k = 1; k < NEXP; k++) if (i >= toff[k]) e = k;
      int lt = i - toff[e];
      int c = counts[e];
      table1[i] = make_int4(e, offsets[e] + lt * 128, min(128, c - lt * 128), 0);
    } else {
      table1[i] = make_int4(-1, 0, 0, 0);
    }
  }
}

// ---------------- scatter: ballot-ordered per-expert slot lists ------------
__global__ __launch_bounds__(256) void scatter_kernel(
    const int* __restrict__ top_e, const float* __restrict__ top_w,
    int* __restrict__ meta, int* __restrict__ slot_token, float* __restrict__ slot_w,
    int* __restrict__ slot_pos) {
  int t = blockIdx.x * 256 + threadIdx.x;
  int lane = threadIdx.x & 63;
  int* cursor = meta + 16; const int* offsets = meta + 32;
#pragma unroll
  for (int k = 0; k < 2; k++) {
    int e = top_e[2 * t + k];
    unsigned long long same = 0;
#pragma unroll
    for (int ee = 0; ee < NEXP; ee++) {
      unsigned long long m = __ballot(e == ee);
      if (ee == e) same = m;
    }
    int leader = __ffsll((long long)same) - 1;
    int base = 0;
    if (lane == leader) base = atomicAdd(&cursor[e], __popcll(same));
    base = __shfl(base, leader);
    int pos = offsets[e] + base + (int)__popcll(same & ((1ull << lane) - 1ull));
    slot_token[pos] = t; slot_w[pos] = top_w[2 * t + k];
    slot_pos[2 * t + k] = pos;
  }
  slot_token[NROUTED + t] = t;           // shared-expert slot
}

// ---------------- GEMM1 (dual): G = silu(A W1^T) * (A W3^T) ---------------
// 128m x 128n x BK=32, 512 thr, 8 waves of 32m x 64n (full-line n-ownership).
// LDS 34.8KB -> 4 blocks/CU. XCD swizzle: b&7 owns nblocks {b&7, b&7+8}.
__global__ __launch_bounds__(512, 4) void gemm1_dual(
    const __bf16* __restrict__ Abase, const __bf16* __restrict__ B1base,
    const __bf16* __restrict__ B3base, const int4* __restrict__ table,
    const int* __restrict__ slot_token, __bf16* __restrict__ Gout) {
  const int K = DDIM, N = HDIM;
  int b = blockIdx.x;
  int j0 = b >> 3;
  int tile = j0 % MAX_T1;
  int nbk = (b & 7) + 8 * (j0 / MAX_T1);
  int4 te = table[tile];
  if (te.x < 0) return;
  const int expert = te.x, slot0 = te.y, rows = te.z;
  const int n0 = nbk * 128;
  const int tid = threadIdx.x, lane = tid & 63, wave = tid >> 6;
  const int wm = (wave & 3) * 32, wn = (wave >> 2) * 64;

  __shared__ __align__(16) unsigned char lds[34816];  // staging 24K | epi 34.8K

  // staging: thread -> row r=tid>>2 (0..127), phys chunk pc=tid&3 (16B each)
  const int r = tid >> 2, pc = tid & 3;
  const int rr = min(r, rows - 1);
  const int koff = (pc ^ (r & 3)) << 3;          // swizzled logical k offset
  const __bf16* aptr = Abase + (size_t)slot_token[slot0 + rr] * K + koff;
  const __bf16* b1p = B1base + (size_t)expert * N * K + (size_t)(n0 + r) * K + koff;
  const __bf16* b3p = B3base + (size_t)expert * N * K + (size_t)(n0 + r) * K + koff;

  f32x4 acc1[2][4] = {};
  f32x4 acc3[2][4] = {};
  const int q = lane >> 4, ln = lane & 15;
  const int ch = (q ^ (ln & 3)) << 4;            // lane's phys chunk byte off

  for (int k0 = 0; k0 < K; k0 += 32) {
    gload16(aptr + k0, lds + wave * 1024);
    gload16(b1p + k0, lds + 8192 + wave * 1024);
    gload16(b3p + k0, lds + 16384 + wave * 1024);
    __syncthreads();
    bf16x8 af[2], b1f[4], b3f[4];
#pragma unroll
    for (int i = 0; i < 2; i++) {
      int row = wm + 16 * i + ln;
      af[i] = *(const bf16x8*)(lds + row * 64 + ch);
    }
#pragma unroll
    for (int j = 0; j < 4; j++) {
      int col = wn + 16 * j + ln;
      b1f[j] = *(const bf16x8*)(lds + 8192 + col * 64 + ch);
      b3f[j] = *(const bf16x8*)(lds + 16384 + col * 64 + ch);
    }
#pragma unroll
    for (int i = 0; i < 2; i++) {
#pragma unroll
      for (int j = 0; j < 4; j++) {
        acc1[i][j] = __builtin_amdgcn_mfma_f32_16x16x32_bf16(af[i], b1f[j], acc1[i][j], 0, 0, 0);
        acc3[i][j] = __builtin_amdgcn_mfma_f32_16x16x32_bf16(af[i], b3f[j], acc3[i][j], 0, 0, 0);
      }
    }
    __syncthreads();
  }

  // ---- epilogue: silu-combine -> wave-local transpose -> 128B line stores
  __bf16* wbuf = (__bf16*)lds + wave * (32 * 68);
#pragma unroll
  for (int i = 0; i < 2; i++) {
#pragma unroll
    for (int j = 0; j < 4; j++) {
#pragma unroll
      for (int rg = 0; rg < 4; rg++) {
        float c1 = acc1[i][j][rg], c3 = acc3[i][j][rg];
        float g = (c1 / (1.f + __expf(-c1))) * c3;
        wbuf[(16 * i + 4 * q + rg) * 68 + 16 * j + ln] = (__bf16)g;
      }
    }
  }
  LDS_FENCE();
#pragma unroll
  for (int i2 = 0; i2 < 4; i2++) {
    int m = i2 * 8 + (lane >> 3);
    int n = (lane & 7) * 8;
    if (wm + m < rows) {
      bf16x8 v = *(const bf16x8*)(wbuf + m * 68 + n);
      *(bf16x8*)(Gout + (size_t)(slot0 + wm + m) * N + n0 + wn + n) = v;
    }
  }
}

// ---------------- GEMM2: y_slot = G W2^T ----------------------------------
// 128m x 128n x BK=32, 512 thr, 8 waves of 32m x 64n. A contiguous slots.
__global__ __launch_bounds__(512, 4) void gemm2_single(
    const __bf16* __restrict__ Abase, const __bf16* __restrict__ Bbase,
    const int4* __restrict__ table, __bf16* __restrict__ ys) {
  const int K = HDIM, N = DDIM;
  int b = blockIdx.x;
  int tile = b >> 3, nbk = b & 7;
  int4 te = table[tile];
  if (te.x < 0) return;
  const int expert = te.x, slot0 = te.y, rows = te.z;
  const int n0 = nbk * 128;
  const int tid = threadIdx.x, lane = tid & 63, wave = tid >> 6;
  const int wm = (wave & 3) * 32, wn = (wave >> 2) * 64;

  __shared__ __align__(16) unsigned char lds[34816];  // staging 16K | epi 34.8K

  const int r = tid >> 2, pc = tid & 3;
  const int rr = min(r, rows - 1);
  const int koff = (pc ^ (r & 3)) << 3;
  const __bf16* aptr = Abase + (size_t)(slot0 + rr) * K + koff;
  const __bf16* bp = Bbase + (size_t)expert * N * K + (size_t)(n0 + r) * K + koff;

  f32x4 acc[2][4] = {};
  const int q = lane >> 4, ln = lane & 15;
  const int ch = (q ^ (ln & 3)) << 4;

  for (int k0 = 0; k0 < K; k0 += 32) {
    gload16(aptr + k0, lds + wave * 1024);
    gload16(bp + k0, lds + 8192 + wave * 1024);
    __syncthreads();
    bf16x8 af[2], bf[4];
#pragma unroll
    for (int i = 0; i < 2; i++) {
      int row = wm + 16 * i + ln;
      af[i] = *(const bf16x8*)(lds + row * 64 + ch);
    }
#pragma unroll
    for (int j = 0; j < 4; j++) {
      int col = wn + 16 * j + ln;
      bf[j] = *(const bf16x8*)(lds + 8192 + col * 64 + ch);
    }
#pragma unroll
    for (int i = 0; i < 2; i++) {
#pragma unroll
      for (int j = 0; j < 4; j++)
        acc[i][j] = __builtin_amdgcn_mfma_f32_16x16x32_bf16(af[i], bf[j], acc[i][j], 0, 0, 0);
    }
    __syncthreads();
  }

  __bf16* wbuf = (__bf16*)lds + wave * (32 * 68);
#pragma unroll
  for (int i = 0; i < 2; i++) {
#pragma unroll
    for (int j = 0; j < 4; j++) {
#pragma unroll
      for (int rg = 0; rg < 4; rg++)
        wbuf[(16 * i + 4 * q + rg) * 68 + 16 * j + ln] = (__bf16)acc[i][j][rg];
    }
  }
  LDS_FENCE();
#pragma unroll
  for (int i2 = 0; i2 < 4; i2++) {
    int m = i2 * 8 + (lane >> 3);
    int n = (lane & 7) * 8;
    if (wm + m < rows) {
      bf16x8 v = *(const bf16x8*)(wbuf + m * 68 + n);
      *(bf16x8*)(ys + (size_t)(slot0 + wm + m) * N + n0 + wn + n) = v;
    }
  }
}

// ---------------- combine: y[t] = w1*ys[p1] + w2*ys[p2] + ys[shared] -------
__global__ __launch_bounds__(256) void combine_kernel(
    const __bf16* __restrict__ ys, const int* __restrict__ slot_pos,
    const float* __restrict__ slot_w, float* __restrict__ y) {
  int t = blockIdx.x, d = threadIdx.x * 4;
  int p1 = slot_pos[2 * t], p2 = slot_pos[2 * t + 1];
  float w1 = slot_w[p1], w2 = slot_w[p2];
  bf16x4 a = *(const bf16x4*)(ys + (size_t)p1 * DDIM + d);
  bf16x4 b = *(const bf16x4*)(ys + (size_t)p2 * DDIM + d);
  bf16x4 c = *(const bf16x4*)(ys + (size_t)(NROUTED + t) * DDIM + d);
  f32x4 o;
#pragma unroll
  for (int i = 0; i < 4; i++)
    o[i] = fmaf(w1, (float)a[i], fmaf(w2, (float)b[i], (float)c[i]));
  *(f32x4*)(y + (size_t)t * DDIM + d) = o;
}

// ---------------------------------------------------------------------------
extern "C" void kernel_launch(void* const* d_in, const int* in_sizes, int n_in,
                              void* d_out, int out_size, void* d_ws, size_t ws_size,
                              hipStream_t stream) {
  const float* h   = (const float*)d_in[0];
  const float* sw1 = (const float*)d_in[1];
  const float* sw2 = (const float*)d_in[2];
  const float* sw3 = (const float*)d_in[3];
  const float* W1  = (const float*)d_in[4];
  const float* W2  = (const float*)d_in[5];
  const float* W3  = (const float*)d_in[6];
  const float* Wg  = (const float*)d_in[7];
  float* y = (float*)d_out;

  char* ws = (char*)d_ws;
  int*   meta       = (int*)ws;                               // 256 B
  int*   top_e      = (int*)(ws + 256);                       // 64 KB
  float* top_w      = (float*)(ws + 256 + 65536);             // 64 KB
  int*   slot_token = (int*)(ws + 256 + 131072);              // 96 KB
  float* slot_w     = (float*)(ws + 256 + 131072 + 98304);    // 96 KB
  int*   slot_pos   = (int*)(ws + 256 + 131072 + 196608);     // 64 KB
  int4*  table1     = (int4*)(ws + 256 + 131072 + 262144);    // 3.2 KB
  size_t off = 0x80000;
  __bf16* h_bf = (__bf16*)(ws + off); off += (size_t)T_TOK * DDIM * 2;      // 16 MB
  size_t w13_off = off;
  __bf16* w1c  = (__bf16*)(ws + off); off += (size_t)9 * HDIM * DDIM * 2;   // 37.75 MB
  __bf16* w3c  = (__bf16*)(ws + off); off += (size_t)9 * HDIM * DDIM * 2;   // 37.75 MB
  __bf16* w2c  = (__bf16*)(ws + off); off += (size_t)9 * DDIM * HDIM * 2;   // 37.75 MB
  __bf16* G    = (__bf16*)(ws + off); off += (size_t)NSLOT * HDIM * 2;      // 100.7 MB
  // y_slot overlays w1c/w3c (dead after gemm1): 50.3 MB < 75.5 MB
  __bf16* yslot = (__bf16*)(ws + w13_off);

  hipMemsetAsync(meta, 0, 256, stream);

  const size_t WB = (size_t)HDIM * DDIM;
  CvtArgs ca;
  ca.s[0] = h;   ca.d[0] = h_bf;
  ca.s[1] = W1;  ca.d[1] = w1c;
  ca.s[2] = sw1; ca.d[2] = w1c + NEXP * WB;
  ca.s[3] = W3;  ca.d[3] = w3c;
  ca.s[4] = sw3; ca.d[4] = w3c + NEXP * WB;
  ca.s[5] = W2;  ca.d[5] = w2c;
  ca.s[6] = sw2; ca.d[6] = w2c + NEXP * WB;
  cvt_fused<<<63488, 256, 0, stream>>>(ca);   // 16252928 vec4s / 256

  gate_kernel<<<T_TOK / 4, 256, 0, stream>>>(h, Wg, top_e, top_w, meta);
  build_meta<<<1, 64, 0, stream>>>(meta, table1);
  scatter_kernel<<<T_TOK / 256, 256, 0, stream>>>(top_e, top_w, meta,
                                                  slot_token, slot_w, slot_pos);

  gemm1_dual<<<MAX_T1 * (HDIM / 128), 512, 0, stream>>>(
      h_bf, w1c, w3c, table1, slot_token, G);
  gemm2_single<<<MAX_T1 * (DDIM / 128), 512, 0, stream>>>(
      G, w2c, table1, yslot);
  combine_kernel<<<T_TOK, 256, 0, stream>>>(yslot, slot_pos, slot_w, y);
}